// Round 8
// baseline (146.609 us; speedup 1.0000x reference)
//
#include <hip/hip_runtime.h>

// QRNN: SEQ=4096, BATCH=8, CIN=256, HID=256, K=2 (lookback=1)
// R10: R9 (best, 138.0us) + X-pack folded into gemm: A-operand reg-staged from
//      fp32 X directly (global dwordx4 -> f2bf -> ds_write_b128, same swizzled
//      LDS layout), tap/pad handled by signed-offset test (off<0 <=> s==0 tap0).
//      pack_kernel now W-only (1024 blocks). Kills 64MB read + 33.6MB write +
//      33.6MB re-read (~15us HBM + a launch gap). B staging unchanged (async).
//
// ws: zbf 16MB | fbf 16MB | (free 16.8MB) | Bm 0.5MB ; Ac/Cc/Hs in free region

#define SEQn 4096
#define NCH 2048          // BATCH*HID channels
#define CHUNK 32
#define NCHUNK 128

typedef __attribute__((ext_vector_type(8))) short bf16x8;
typedef __attribute__((ext_vector_type(4))) float floatx4;

__device__ __forceinline__ unsigned short f2bf(float x) {
  unsigned int u = __float_as_uint(x);
  u += 0x7fffu + ((u >> 16) & 1u);     // RNE
  return (unsigned short)(u >> 16);
}
__device__ __forceinline__ float bf2f(ushort u) {
  return __uint_as_float((unsigned int)u << 16);
}
__device__ __forceinline__ float sigf(float x) {
  return __builtin_amdgcn_rcpf(1.0f + __expf(-x));
}

// ---- 1) pack W only: 1024 blocks ----
__global__ void pack_kernel(const float* __restrict__ Wz, const float* __restrict__ Wf,
                            ushort* __restrict__ Bm) {
  int idx = blockIdx.x * 256 + threadIdx.x;        // 0..262143
  int n = idx >> 9, kin = idx & 511;
  const float* W = (n < 256) ? Wz : Wf;
  int h = n & 255, c = kin & 255, tap = kin >> 8;  // kin<256: tap0 (X[s-1])
  Bm[idx] = f2bf(W[h * 512 + c * 2 + tap]);
}

// ---- 2) GEMM 64x128, BK=64, mfma_f32_16x16x32_bf16, swizzled LDS ----
// LDS seg (row, s) holds global k-seg s^(row&7)  (seg = 16B = 8 bf16)
// 1D grid 2048: bn=(id>>3)&3, bm=((id>>5)<<3)|(id&7) -> A-panel sharers same XCD.
// A staged from fp32 X in-registers (f2bf), B via global_load_lds from Bm.
__global__ __launch_bounds__(256) void gemm_kernel(
    const float* __restrict__ Xf, const ushort* __restrict__ Bm,
    const float* __restrict__ bz, const float* __restrict__ bfb,
    ushort* __restrict__ zout, ushort* __restrict__ fout) {
  __shared__ __align__(16) char smem_raw[24576];
  ushort* sA = (ushort*)smem_raw;                 // 64 rows x 64 k   (8KB)
  ushort* sB = sA + 4096;                         // 128 cols x 64 k  (16KB)
  ushort* sT = (ushort*)smem_raw;                 // epilogue 64 x 136 (17.4KB)

  const int tid  = threadIdx.x;
  const int wave = tid >> 6;
  const int lane = tid & 63;
  const int quad = lane >> 4;
  const int lrow = lane & 15;
  const int wm = wave >> 1;          // 2x2 wave grid, each 32x64 output
  const int wn = wave & 1;
  const int id = blockIdx.x;         // 0..2047
  const int bn = (id >> 3) & 3;      // 0..3 (0,1=Z; 2,3=F)
  const int bm = ((id >> 5) << 3) | (id & 7);   // 0..511

  floatx4 acc[2][4];
#pragma unroll
  for (int i = 0; i < 2; ++i)
#pragma unroll
    for (int j = 0; j < 4; ++j)
      acc[i][j] = (floatx4){0.f, 0.f, 0.f, 0.f};

  // staging coords: A 2 segs/thread (512 segs), B 4 segs/thread (1024 segs)
  int rowA[2], gkoA[2], rowB[4], gkoB[4];
#pragma unroll
  for (int it = 0; it < 2; ++it) {
    int g = it * 256 + wave * 64 + lane;     // 0..511
    int row = g >> 3, s = g & 7;
    rowA[it] = row;                          // 0..63
    gkoA[it] = (s ^ (row & 7)) * 8;
  }
#pragma unroll
  for (int it = 0; it < 4; ++it) {
    int g = it * 256 + wave * 64 + lane;     // 0..1023
    int row = g >> 3, s = g & 7;
    rowB[it] = row;                          // 0..127
    gkoB[it] = (s ^ (row & 7)) * 8;
  }
  char* ldsA = smem_raw + wave * 1024 + (lane << 4);
  char* ldsB = smem_raw + 8192 + wave * 1024 + (lane << 4);

  const ushort* Brow = Bm + (size_t)(bn * 128) * 512;

  for (int k0 = 0; k0 < 512; k0 += 64) {
    __syncthreads();                 // prev iter ds_reads done
    // B first: async global->LDS, no reg dependency
#pragma unroll
    for (int it = 0; it < 4; ++it) {
      const int kk = k0 + gkoB[it];
      __builtin_amdgcn_global_load_lds(
          (const __attribute__((address_space(1))) void*)(Brow + (size_t)rowB[it] * 512 + kk),
          (__attribute__((address_space(3))) void*)(ldsB + it * 4096), 16, 0, 0);
    }
    // A: reg-stage from fp32 X, convert, ds_write (same swizzled layout)
#pragma unroll
    for (int it = 0; it < 2; ++it) {
      const int kk = k0 + gkoA[it];
      const long off = (long)(bm * 64 + rowA[it]) * 256
                     + ((kk < 256) ? kk : kk + 1792) - 2048;
      float4 v0 = {0.f, 0.f, 0.f, 0.f}, v1 = {0.f, 0.f, 0.f, 0.f};
      if (off >= 0) {                // off<0 <=> s==0 tap0 (zero pad)
        v0 = *(const float4*)(Xf + off);
        v1 = *(const float4*)(Xf + off + 4);
      }
      uint4 w;
      w.x = (unsigned)f2bf(v0.x) | ((unsigned)f2bf(v0.y) << 16);
      w.y = (unsigned)f2bf(v0.z) | ((unsigned)f2bf(v0.w) << 16);
      w.z = (unsigned)f2bf(v1.x) | ((unsigned)f2bf(v1.y) << 16);
      w.w = (unsigned)f2bf(v1.z) | ((unsigned)f2bf(v1.w) << 16);
      *(uint4*)(ldsA + it * 4096) = w;
    }
    __syncthreads();                 // drains lgkm (A ds_write) + vmcnt (B)

    bf16x8 af[2][2], bfr[4][2];
#pragma unroll
    for (int fi = 0; fi < 2; ++fi) {
      const int r = wm * 32 + fi * 16 + lrow;
#pragma unroll
      for (int ks = 0; ks < 2; ++ks) {
        const int s = (ks * 4 + quad) ^ (r & 7);
        af[fi][ks] = *(const bf16x8*)&sA[r * 64 + s * 8];
      }
    }
#pragma unroll
    for (int fj = 0; fj < 4; ++fj) {
      const int r = wn * 64 + fj * 16 + lrow;
#pragma unroll
      for (int ks = 0; ks < 2; ++ks) {
        const int s = (ks * 4 + quad) ^ (r & 7);
        bfr[fj][ks] = *(const bf16x8*)&sB[r * 64 + s * 8];
      }
    }
#pragma unroll
    for (int ks = 0; ks < 2; ++ks)
#pragma unroll
      for (int fi = 0; fi < 2; ++fi)
#pragma unroll
        for (int fj = 0; fj < 4; ++fj)
          acc[fi][fj] = __builtin_amdgcn_mfma_f32_16x16x32_bf16(af[fi][ks], bfr[fj][ks], acc[fi][fj], 0, 0, 0);
  }

  // epilogue: activation -> bf16 -> sT (64 x 136 padded) -> coalesced dwordx4
  const bool isZ = (bn < 2);
  ushort* gout = isZ ? zout : fout;
  const int ncol0 = (bn & 1) * 128;
  const float* bias = isZ ? bz : bfb;
  float bv[4];
#pragma unroll
  for (int fj = 0; fj < 4; ++fj)
    bv[fj] = bias[ncol0 + wn * 64 + fj * 16 + lrow];

  __syncthreads();                   // all ds_reads of sA/sB done (sT aliases)
#pragma unroll
  for (int fi = 0; fi < 2; ++fi)
#pragma unroll
    for (int fj = 0; fj < 4; ++fj)
#pragma unroll
      for (int r = 0; r < 4; ++r) {
        float v = acc[fi][fj][r] + bv[fj];
        float o = isZ ? (v * sigf(1.702f * v)) : sigf(v);
        sT[(wm * 32 + fi * 16 + quad * 4 + r) * 136 + wn * 64 + fj * 16 + lrow] = f2bf(o);
      }
  __syncthreads();
#pragma unroll
  for (int it = 0; it < 4; ++it) {
    int e = tid + it * 256;           // 1024 segs = 64 rows x 16 segs
    int row = e >> 4, seg = e & 15;
    uint4 v = *(uint4*)&sT[row * 136 + seg * 8];
    *(uint4*)(gout + (size_t)(bm * 64 + row) * 256 + ncol0 + seg * 8) = v;
  }
}

// ---- 3) per-chunk reduction, 2 channels/thread ----
__global__ void scanA_kernel(const ushort* __restrict__ z, const ushort* __restrict__ f,
                             float* __restrict__ Ac, float* __restrict__ Cc) {
  int t = blockIdx.x * blockDim.x + threadIdx.x;   // 0..131071
  int ch2 = t & 1023;
  int j = t >> 10;                                  // 0..127
  const size_t base = (size_t)j * CHUNK * NCH + 2 * ch2;
  const ushort* zp = z + base;
  const ushort* fp = f + base;
  float A0 = 1.0f, C0 = 0.0f, A1 = 1.0f, C1 = 0.0f;
#pragma unroll
  for (int i = 0; i < CHUNK; ++i) {
    ushort2 fv = *(const ushort2*)(fp + (size_t)i * NCH);
    ushort2 zv = *(const ushort2*)(zp + (size_t)i * NCH);
    float f0 = bf2f(fv.x), f1 = bf2f(fv.y);
    float a0 = 1.0f - f0, a1 = 1.0f - f1;
    C0 = fmaf(a0, C0, f0 * bf2f(zv.x)); A0 *= a0;
    C1 = fmaf(a1, C1, f1 * bf2f(zv.y)); A1 *= a1;
  }
  float2 Av = {A0, A1}, Cv = {C0, C1};
  *(float2*)(Ac + (size_t)j * NCH + 2 * ch2) = Av;
  *(float2*)(Cc + (size_t)j * NCH + 2 * ch2) = Cv;
}

// ---- 4) cross-chunk scan: one wave per channel, shfl Hillis-Steele ----
__global__ void scanB_kernel(const float* __restrict__ hidden,
                             const float* __restrict__ Ac, const float* __restrict__ Cc,
                             float* __restrict__ Hs) {
  const int lane = threadIdx.x & 63;
  const int ch = blockIdx.x * 4 + (threadIdx.x >> 6);   // 512 blocks x 4 waves
  const int j0 = 2 * lane, j1 = 2 * lane + 1;
  float a0 = Ac[j0 * NCH + ch], c0 = Cc[j0 * NCH + ch];
  float a1 = Ac[j1 * NCH + ch], c1 = Cc[j1 * NCH + ch];
  float a = a0 * a1;
  float c = fmaf(a1, c0, c1);
#pragma unroll
  for (int d = 1; d < 64; d <<= 1) {
    float pa = __shfl_up(a, d, 64);
    float pc = __shfl_up(c, d, 64);
    if (lane >= d) { c = fmaf(a, pc, c); a *= pa; }
  }
  float xa = __shfl_up(a, 1, 64), xc = __shfl_up(c, 1, 64);
  if (lane == 0) { xa = 1.0f; xc = 0.0f; }
  float h0 = hidden[ch];
  float hs0 = fmaf(xa, h0, xc);
  Hs[j0 * NCH + ch] = hs0;
  Hs[j1 * NCH + ch] = fmaf(a0, hs0, c0);
}

// ---- 5) replay within chunk, 2 channels/thread, fp32 out ----
__global__ void scanC_kernel(const ushort* __restrict__ z, const ushort* __restrict__ f,
                             const float* __restrict__ Hs, float* __restrict__ out) {
  int t = blockIdx.x * blockDim.x + threadIdx.x;   // 0..131071
  int ch2 = t & 1023;
  int j = t >> 10;
  float2 hv = *(const float2*)(Hs + (size_t)j * NCH + 2 * ch2);
  float h0 = hv.x, h1 = hv.y;
  const size_t base = (size_t)j * CHUNK * NCH + 2 * ch2;
  const ushort* zp = z + base;
  const ushort* fp = f + base;
  float* op = out + base;
#pragma unroll
  for (int i = 0; i < CHUNK; ++i) {
    ushort2 fv = *(const ushort2*)(fp + (size_t)i * NCH);
    ushort2 zv = *(const ushort2*)(zp + (size_t)i * NCH);
    float f0 = bf2f(fv.x), f1 = bf2f(fv.y);
    h0 = fmaf(f0, bf2f(zv.x) - h0, h0);
    h1 = fmaf(f1, bf2f(zv.y) - h1, h1);
    float2 o = {h0, h1};
    *(float2*)(op + (size_t)i * NCH) = o;
  }
  if (j == NCHUNK - 1) {
    float2 o = {h0, h1};
    *(float2*)(out + (size_t)SEQn * NCH + 2 * ch2) = o;   // h_last row
  }
}

extern "C" void kernel_launch(void* const* d_in, const int* in_sizes, int n_in,
                              void* d_out, int out_size, void* d_ws, size_t ws_size,
                              hipStream_t stream) {
  const float* X      = (const float*)d_in[0];
  const float* hidden = (const float*)d_in[1];
  const float* Wz     = (const float*)d_in[2];
  const float* bz     = (const float*)d_in[3];
  const float* Wf     = (const float*)d_in[4];
  const float* bfb    = (const float*)d_in[5];
  float* out = (float*)d_out;

  char* ws = (char*)d_ws;
  ushort* zbf = (ushort*)ws;                       // 16,777,216 B
  ushort* fbf = (ushort*)(ws + 16777216);          // 16,777,216 B
  ushort* Bm  = (ushort*)(ws + 50335744);          //    524,288 B
  float* Ac = (float*)(ws + 33554432);             // 1 MB
  float* Cc = (float*)(ws + 34603008);             // 1 MB
  float* Hs = (float*)(ws + 35651584);             // 1 MB

  pack_kernel<<<1024, 256, 0, stream>>>(Wz, Wf, Bm);
  gemm_kernel<<<2048, 256, 0, stream>>>(X, Bm, bz, bfb, zbf, fbf);
  scanA_kernel<<<512, 256, 0, stream>>>(zbf, fbf, Ac, Cc);
  scanB_kernel<<<512, 256, 0, stream>>>(hidden, Ac, Cc, Hs);
  scanC_kernel<<<512, 256, 0, stream>>>(zbf, fbf, Hs, out);
}

// Round 9
// 142.013 us; speedup vs baseline: 1.0324x; 1.0324x over previous
//
#include <hip/hip_runtime.h>

// QRNN: SEQ=4096, BATCH=8, CIN=256, HID=256, K=2 (lookback=1)
// R11: R9 (verified best, 138.0us) + 2-phase double-buffered gemm K-loop:
//      STAGE(t+1) issued BEFORE ds_read+MFMA of tile t, ONE barrier per step
//      (drain overlaps the compute phase). LDS 2x24KB=48KB -> cap 3 blocks/CU
//      (= currently achieved residency, so no R6-style occupancy loss).
//      R10's sync A-fold reverted (+8.6us regression, VALUBusy 24->36).
//
// ws: zbf 16MB | fbf 16MB | Xbf 16MB (dead after gemm; Ac/Cc/Hs aliased) | Bm 0.5MB

#define SEQn 4096
#define NCH 2048          // BATCH*HID channels
#define CHUNK 32
#define NCHUNK 128

typedef __attribute__((ext_vector_type(8))) short bf16x8;
typedef __attribute__((ext_vector_type(4))) float floatx4;

__device__ __forceinline__ unsigned short f2bf(float x) {
  unsigned int u = __float_as_uint(x);
  u += 0x7fffu + ((u >> 16) & 1u);     // RNE
  return (unsigned short)(u >> 16);
}
__device__ __forceinline__ float bf2f(ushort u) {
  return __uint_as_float((unsigned int)u << 16);
}
__device__ __forceinline__ float sigf(float x) {
  return __builtin_amdgcn_rcpf(1.0f + __expf(-x));
}

// ---- 1) merged pack: blocks [0,1024) pack W, blocks [1024,9218) pack X ----
__global__ void pack_kernel(const float* __restrict__ X,
                            const float* __restrict__ Wz, const float* __restrict__ Wf,
                            ushort* __restrict__ Xbf, ushort* __restrict__ Bm) {
  if (blockIdx.x < 1024) {
    int idx = blockIdx.x * 256 + threadIdx.x;        // 0..262143
    int n = idx >> 9, kin = idx & 511;
    const float* W = (n < 256) ? Wz : Wf;
    int h = n & 255, c = kin & 255, tap = kin >> 8;  // kin<256: tap0 (X[s-1])
    Bm[idx] = f2bf(W[h * 512 + c * 2 + tap]);
  } else {
    int idx = (blockIdx.x - 1024) * 256 + threadIdx.x;
    const int total4 = ((SEQn + 1) * NCH) / 4;       // 2,097,664
    if (idx >= total4) return;
    const int pad4 = NCH / 4;
    float4 v;
    if (idx < pad4) { v.x = 0.f; v.y = 0.f; v.z = 0.f; v.w = 0.f; }
    else v = ((const float4*)X)[idx - pad4];
    ushort4 o;
    o.x = f2bf(v.x); o.y = f2bf(v.y); o.z = f2bf(v.z); o.w = f2bf(v.w);
    ((ushort4*)Xbf)[idx] = o;
  }
}

// ---- 2) GEMM 64x128, BK=64, mfma_f32_16x16x32_bf16, swizzled LDS, 2-phase dbuf ----
// LDS seg (row, s) holds global k-seg s^(row&7)  (seg = 16B = 8 bf16)
// 1D grid 2048: bn=(id>>3)&3, bm=((id>>5)<<3)|(id&7) -> A-panel sharers same XCD.
__global__ __launch_bounds__(256) void gemm_kernel(
    const ushort* __restrict__ Xbf, const ushort* __restrict__ Bm,
    const float* __restrict__ bz, const float* __restrict__ bfb,
    ushort* __restrict__ zout, ushort* __restrict__ fout) {
  __shared__ __align__(16) char smem_raw[49152];
  // buffer c at c*24576: sA 64x64 (8KB) then sB 128x64 (16KB)
  ushort* sT = (ushort*)smem_raw;                 // epilogue 64 x 136 (17.4KB)

  const int tid  = threadIdx.x;
  const int wave = tid >> 6;
  const int lane = tid & 63;
  const int quad = lane >> 4;
  const int lrow = lane & 15;
  const int wm = wave >> 1;          // 2x2 wave grid, each 32x64 output
  const int wn = wave & 1;
  const int id = blockIdx.x;         // 0..2047
  const int bn = (id >> 3) & 3;      // 0..3 (0,1=Z; 2,3=F)
  const int bm = ((id >> 5) << 3) | (id & 7);   // 0..511

  floatx4 acc[2][4];
#pragma unroll
  for (int i = 0; i < 2; ++i)
#pragma unroll
    for (int j = 0; j < 4; ++j)
      acc[i][j] = (floatx4){0.f, 0.f, 0.f, 0.f};

  // staging coords: A 2 segs/thread (512 segs), B 4 segs/thread (1024 segs)
  int rowA[2], gkoA[2], rowB[4], gkoB[4];
#pragma unroll
  for (int it = 0; it < 2; ++it) {
    int g = it * 256 + wave * 64 + lane;     // 0..511
    int row = g >> 3, s = g & 7;
    rowA[it] = row;                          // 0..63
    gkoA[it] = (s ^ (row & 7)) * 8;
  }
#pragma unroll
  for (int it = 0; it < 4; ++it) {
    int g = it * 256 + wave * 64 + lane;     // 0..1023
    int row = g >> 3, s = g & 7;
    rowB[it] = row;                          // 0..127
    gkoB[it] = (s ^ (row & 7)) * 8;
  }

  const ushort* Arow = Xbf + (size_t)(bm * 64) * 256;
  const ushort* Brow = Bm + (size_t)(bn * 128) * 512;

#define STAGE(curb, k0)                                                          \
  {                                                                              \
    char* lA = smem_raw + (curb) * 24576 + wave * 1024 + (lane << 4);            \
    char* lB = lA + 8192;                                                        \
    _Pragma("unroll")                                                            \
    for (int it = 0; it < 2; ++it) {                                             \
      const int kk = (k0) + gkoA[it];                                            \
      const int cA = (kk < 256) ? kk : kk + 1792;  /* tap1 lives +2048-256 */    \
      __builtin_amdgcn_global_load_lds(                                          \
          (const __attribute__((address_space(1))) void*)(Arow + (size_t)rowA[it] * 256 + cA), \
          (__attribute__((address_space(3))) void*)(lA + it * 4096), 16, 0, 0);  \
    }                                                                            \
    _Pragma("unroll")                                                            \
    for (int it = 0; it < 4; ++it) {                                             \
      const int kk = (k0) + gkoB[it];                                            \
      __builtin_amdgcn_global_load_lds(                                          \
          (const __attribute__((address_space(1))) void*)(Brow + (size_t)rowB[it] * 512 + kk), \
          (__attribute__((address_space(3))) void*)(lB + it * 4096), 16, 0, 0);  \
    }                                                                            \
  }

  STAGE(0, 0);
  __syncthreads();                   // tile0 ready (implicit vmcnt drain)

  int cur = 0;
  for (int t = 0; t < 8; ++t) {
    if (t < 7) STAGE(cur ^ 1, (t + 1) * 64);   // prefetch next tile, in flight during compute

    const ushort* sA = (const ushort*)(smem_raw + cur * 24576);
    const ushort* sB = sA + 4096;              // +8192 bytes

    bf16x8 af[2][2], bfr[4][2];
#pragma unroll
    for (int fi = 0; fi < 2; ++fi) {
      const int r = wm * 32 + fi * 16 + lrow;
#pragma unroll
      for (int ks = 0; ks < 2; ++ks) {
        const int s = (ks * 4 + quad) ^ (r & 7);
        af[fi][ks] = *(const bf16x8*)&sA[r * 64 + s * 8];
      }
    }
#pragma unroll
    for (int fj = 0; fj < 4; ++fj) {
      const int r = wn * 64 + fj * 16 + lrow;
#pragma unroll
      for (int ks = 0; ks < 2; ++ks) {
        const int s = (ks * 4 + quad) ^ (r & 7);
        bfr[fj][ks] = *(const bf16x8*)&sB[r * 64 + s * 8];
      }
    }
#pragma unroll
    for (int ks = 0; ks < 2; ++ks)
#pragma unroll
      for (int fi = 0; fi < 2; ++fi)
#pragma unroll
        for (int fj = 0; fj < 4; ++fj)
          acc[fi][fj] = __builtin_amdgcn_mfma_f32_16x16x32_bf16(af[fi][ks], bfr[fj][ks], acc[fi][fj], 0, 0, 0);

    __syncthreads();                 // drains prefetch + guards buffer reuse
    cur ^= 1;
  }
#undef STAGE

  // epilogue: activation -> bf16 -> sT (64 x 136 padded) -> coalesced dwordx4
  const bool isZ = (bn < 2);
  ushort* gout = isZ ? zout : fout;
  const int ncol0 = (bn & 1) * 128;
  const float* bias = isZ ? bz : bfb;
  float bv[4];
#pragma unroll
  for (int fj = 0; fj < 4; ++fj)
    bv[fj] = bias[ncol0 + wn * 64 + fj * 16 + lrow];

#pragma unroll
  for (int fi = 0; fi < 2; ++fi)
#pragma unroll
    for (int fj = 0; fj < 4; ++fj)
#pragma unroll
      for (int r = 0; r < 4; ++r) {
        float v = acc[fi][fj][r] + bv[fj];
        float o = isZ ? (v * sigf(1.702f * v)) : sigf(v);
        sT[(wm * 32 + fi * 16 + quad * 4 + r) * 136 + wn * 64 + fj * 16 + lrow] = f2bf(o);
      }
  __syncthreads();
#pragma unroll
  for (int it = 0; it < 4; ++it) {
    int e = tid + it * 256;           // 1024 segs = 64 rows x 16 segs
    int row = e >> 4, seg = e & 15;
    uint4 v = *(uint4*)&sT[row * 136 + seg * 8];
    *(uint4*)(gout + (size_t)(bm * 64 + row) * 256 + ncol0 + seg * 8) = v;
  }
}

// ---- 3) per-chunk reduction, 2 channels/thread ----
__global__ void scanA_kernel(const ushort* __restrict__ z, const ushort* __restrict__ f,
                             float* __restrict__ Ac, float* __restrict__ Cc) {
  int t = blockIdx.x * blockDim.x + threadIdx.x;   // 0..131071
  int ch2 = t & 1023;
  int j = t >> 10;                                  // 0..127
  const size_t base = (size_t)j * CHUNK * NCH + 2 * ch2;
  const ushort* zp = z + base;
  const ushort* fp = f + base;
  float A0 = 1.0f, C0 = 0.0f, A1 = 1.0f, C1 = 0.0f;
#pragma unroll
  for (int i = 0; i < CHUNK; ++i) {
    ushort2 fv = *(const ushort2*)(fp + (size_t)i * NCH);
    ushort2 zv = *(const ushort2*)(zp + (size_t)i * NCH);
    float f0 = bf2f(fv.x), f1 = bf2f(fv.y);
    float a0 = 1.0f - f0, a1 = 1.0f - f1;
    C0 = fmaf(a0, C0, f0 * bf2f(zv.x)); A0 *= a0;
    C1 = fmaf(a1, C1, f1 * bf2f(zv.y)); A1 *= a1;
  }
  float2 Av = {A0, A1}, Cv = {C0, C1};
  *(float2*)(Ac + (size_t)j * NCH + 2 * ch2) = Av;
  *(float2*)(Cc + (size_t)j * NCH + 2 * ch2) = Cv;
}

// ---- 4) cross-chunk scan: one wave per channel, shfl Hillis-Steele ----
__global__ void scanB_kernel(const float* __restrict__ hidden,
                             const float* __restrict__ Ac, const float* __restrict__ Cc,
                             float* __restrict__ Hs) {
  const int lane = threadIdx.x & 63;
  const int ch = blockIdx.x * 4 + (threadIdx.x >> 6);   // 512 blocks x 4 waves
  const int j0 = 2 * lane, j1 = 2 * lane + 1;
  float a0 = Ac[j0 * NCH + ch], c0 = Cc[j0 * NCH + ch];
  float a1 = Ac[j1 * NCH + ch], c1 = Cc[j1 * NCH + ch];
  float a = a0 * a1;
  float c = fmaf(a1, c0, c1);
#pragma unroll
  for (int d = 1; d < 64; d <<= 1) {
    float pa = __shfl_up(a, d, 64);
    float pc = __shfl_up(c, d, 64);
    if (lane >= d) { c = fmaf(a, pc, c); a *= pa; }
  }
  float xa = __shfl_up(a, 1, 64), xc = __shfl_up(c, 1, 64);
  if (lane == 0) { xa = 1.0f; xc = 0.0f; }
  float h0 = hidden[ch];
  float hs0 = fmaf(xa, h0, xc);
  Hs[j0 * NCH + ch] = hs0;
  Hs[j1 * NCH + ch] = fmaf(a0, hs0, c0);
}

// ---- 5) replay within chunk, 2 channels/thread, fp32 out ----
__global__ void scanC_kernel(const ushort* __restrict__ z, const ushort* __restrict__ f,
                             const float* __restrict__ Hs, float* __restrict__ out) {
  int t = blockIdx.x * blockDim.x + threadIdx.x;   // 0..131071
  int ch2 = t & 1023;
  int j = t >> 10;
  float2 hv = *(const float2*)(Hs + (size_t)j * NCH + 2 * ch2);
  float h0 = hv.x, h1 = hv.y;
  const size_t base = (size_t)j * CHUNK * NCH + 2 * ch2;
  const ushort* zp = z + base;
  const ushort* fp = f + base;
  float* op = out + base;
#pragma unroll
  for (int i = 0; i < CHUNK; ++i) {
    ushort2 fv = *(const ushort2*)(fp + (size_t)i * NCH);
    ushort2 zv = *(const ushort2*)(zp + (size_t)i * NCH);
    float f0 = bf2f(fv.x), f1 = bf2f(fv.y);
    h0 = fmaf(f0, bf2f(zv.x) - h0, h0);
    h1 = fmaf(f1, bf2f(zv.y) - h1, h1);
    float2 o = {h0, h1};
    *(float2*)(op + (size_t)i * NCH) = o;
  }
  if (j == NCHUNK - 1) {
    float2 o = {h0, h1};
    *(float2*)(out + (size_t)SEQn * NCH + 2 * ch2) = o;   // h_last row
  }
}

extern "C" void kernel_launch(void* const* d_in, const int* in_sizes, int n_in,
                              void* d_out, int out_size, void* d_ws, size_t ws_size,
                              hipStream_t stream) {
  const float* X      = (const float*)d_in[0];
  const float* hidden = (const float*)d_in[1];
  const float* Wz     = (const float*)d_in[2];
  const float* bz     = (const float*)d_in[3];
  const float* Wf     = (const float*)d_in[4];
  const float* bfb    = (const float*)d_in[5];
  float* out = (float*)d_out;

  char* ws = (char*)d_ws;
  ushort* zbf = (ushort*)ws;                       // 16,777,216 B
  ushort* fbf = (ushort*)(ws + 16777216);          // 16,777,216 B
  ushort* Xbf = (ushort*)(ws + 33554432);          // 16,781,312 B (dead after gemm)
  ushort* Bm  = (ushort*)(ws + 50335744);          //    524,288 B
  // aliased over Xbf (used only after gemm completes):
  float* Ac = (float*)(ws + 33554432);
  float* Cc = (float*)(ws + 34603008);
  float* Hs = (float*)(ws + 35651584);

  pack_kernel<<<9218, 256, 0, stream>>>(X, Wz, Wf, Xbf, Bm);
  gemm_kernel<<<2048, 256, 0, stream>>>(Xbf, Bm, bz, bfb, zbf, fbf);
  scanA_kernel<<<512, 256, 0, stream>>>(zbf, fbf, Ac, Cc);
  scanB_kernel<<<512, 256, 0, stream>>>(hidden, Ac, Cc, Hs);
  scanC_kernel<<<512, 256, 0, stream>>>(zbf, fbf, Hs, out);
}

// Round 10
// 140.640 us; speedup vs baseline: 1.0424x; 1.0098x over previous
//
#include <hip/hip_runtime.h>

// QRNN: SEQ=4096, BATCH=8, CIN=256, HID=256, K=2 (lookback=1)
// R12: R9 scans/pack (verified) + gemm regeometried for max TLP:
//      tile 64 rows x 256 cols (one full Z or F matrix), 512 thr / 8 waves,
//      BK=64 single-buffer (40KB LDS) -> 4 blocks/CU cap, grid 1024 = exactly
//      4/CU -> 32 waves/CU (vs ~12). Same verified 2-barrier K-step (all
//      pipelining grafts R6/R10/R11 regressed; occupancy wins R7/R9 kept).
//      Z/F pair sharing an A-panel = ids 512 apart = same XCD (512%8==0).
//
// ws: zbf 16MB | fbf 16MB | Xbf 16MB (dead after gemm; Ac/Cc/Hs aliased) | Bm 0.5MB

#define SEQn 4096
#define NCH 2048          // BATCH*HID channels
#define CHUNK 32
#define NCHUNK 128

typedef __attribute__((ext_vector_type(8))) short bf16x8;
typedef __attribute__((ext_vector_type(4))) float floatx4;

__device__ __forceinline__ unsigned short f2bf(float x) {
  unsigned int u = __float_as_uint(x);
  u += 0x7fffu + ((u >> 16) & 1u);     // RNE
  return (unsigned short)(u >> 16);
}
__device__ __forceinline__ float bf2f(ushort u) {
  return __uint_as_float((unsigned int)u << 16);
}
__device__ __forceinline__ float sigf(float x) {
  return __builtin_amdgcn_rcpf(1.0f + __expf(-x));
}

// ---- 1) merged pack: blocks [0,1024) pack W, blocks [1024,9218) pack X ----
__global__ void pack_kernel(const float* __restrict__ X,
                            const float* __restrict__ Wz, const float* __restrict__ Wf,
                            ushort* __restrict__ Xbf, ushort* __restrict__ Bm) {
  if (blockIdx.x < 1024) {
    int idx = blockIdx.x * 256 + threadIdx.x;        // 0..262143
    int n = idx >> 9, kin = idx & 511;
    const float* W = (n < 256) ? Wz : Wf;
    int h = n & 255, c = kin & 255, tap = kin >> 8;  // kin<256: tap0 (X[s-1])
    Bm[idx] = f2bf(W[h * 512 + c * 2 + tap]);
  } else {
    int idx = (blockIdx.x - 1024) * 256 + threadIdx.x;
    const int total4 = ((SEQn + 1) * NCH) / 4;       // 2,097,664
    if (idx >= total4) return;
    const int pad4 = NCH / 4;
    float4 v;
    if (idx < pad4) { v.x = 0.f; v.y = 0.f; v.z = 0.f; v.w = 0.f; }
    else v = ((const float4*)X)[idx - pad4];
    ushort4 o;
    o.x = f2bf(v.x); o.y = f2bf(v.y); o.z = f2bf(v.z); o.w = f2bf(v.w);
    ((ushort4*)Xbf)[idx] = o;
  }
}

// ---- 2) GEMM 64x256 (one matrix), BK=64, mfma_f32_16x16x32_bf16, swizzled LDS ----
// LDS seg (row, s) holds global k-seg s^(row&7)  (seg = 16B = 8 bf16)
// grid 1024: bnZF = id>>9 (0=Z,1=F), bm = id&511. 512 threads, 8 waves,
// wave w owns cols [w*32, w*32+32) x all 64 rows.
__global__ __launch_bounds__(512) void gemm_kernel(
    const ushort* __restrict__ Xbf, const ushort* __restrict__ Bm,
    const float* __restrict__ bz, const float* __restrict__ bfb,
    ushort* __restrict__ zout, ushort* __restrict__ fout) {
  __shared__ __align__(16) char smem_raw[40960];
  ushort* sA = (ushort*)smem_raw;                 // 64 rows x 64 k   (8KB)
  ushort* sB = sA + 4096;                         // 256 cols x 64 k  (32KB)
  ushort* sT = (ushort*)smem_raw;                 // epilogue 64 x 264 (33.8KB)

  const int tid  = threadIdx.x;
  const int wave = tid >> 6;         // 0..7
  const int lane = tid & 63;
  const int quad = lane >> 4;
  const int lrow = lane & 15;
  const int id = blockIdx.x;         // 0..1023
  const int bnZF = id >> 9;          // 0=Z, 1=F
  const int bm = id & 511;           // 0..511

  floatx4 acc[4][2];
#pragma unroll
  for (int i = 0; i < 4; ++i)
#pragma unroll
    for (int j = 0; j < 2; ++j)
      acc[i][j] = (floatx4){0.f, 0.f, 0.f, 0.f};

  // staging coords: A 1 seg/thread (512 segs), B 4 segs/thread (2048 segs)
  const int rowA = tid >> 3;                     // 0..63
  const int gkoA = ((tid & 7) ^ (rowA & 7)) * 8;
  int rowBG[4], gkoB[4];
#pragma unroll
  for (int it = 0; it < 4; ++it) {
    int g = it * 512 + tid;                      // 0..2047
    int row = g >> 3, s = g & 7;                 // row 0..255
    rowBG[it] = bnZF * 256 + row;                // Bm row (Z: 0..255, F: 256..511)
    gkoB[it] = (s ^ (row & 7)) * 8;
  }
  char* ldsA = smem_raw + (tid << 4);
  char* ldsB = smem_raw + 8192 + (tid << 4);

  const ushort* Arow = Xbf + (size_t)(bm * 64) * 256;

  for (int k0 = 0; k0 < 512; k0 += 64) {
    __syncthreads();                 // prev iter ds_reads done
    {
      const int kk = k0 + gkoA;
      const int cA = (kk < 256) ? kk : kk + 1792;     // tap1 lives +2048-256
      __builtin_amdgcn_global_load_lds(
          (const __attribute__((address_space(1))) void*)(Arow + (size_t)rowA * 256 + cA),
          (__attribute__((address_space(3))) void*)ldsA, 16, 0, 0);
    }
#pragma unroll
    for (int it = 0; it < 4; ++it) {
      const int kk = k0 + gkoB[it];
      __builtin_amdgcn_global_load_lds(
          (const __attribute__((address_space(1))) void*)(Bm + (size_t)rowBG[it] * 512 + kk),
          (__attribute__((address_space(3))) void*)(ldsB + it * 8192), 16, 0, 0);
    }
    __syncthreads();

    bf16x8 af[4][2], bfr[2][2];
#pragma unroll
    for (int fi = 0; fi < 4; ++fi) {
      const int r = fi * 16 + lrow;
#pragma unroll
      for (int ks = 0; ks < 2; ++ks) {
        const int s = (ks * 4 + quad) ^ (r & 7);
        af[fi][ks] = *(const bf16x8*)&sA[r * 64 + s * 8];
      }
    }
#pragma unroll
    for (int fj = 0; fj < 2; ++fj) {
      const int r = wave * 32 + fj * 16 + lrow;  // B row = output col
#pragma unroll
      for (int ks = 0; ks < 2; ++ks) {
        const int s = (ks * 4 + quad) ^ (r & 7);
        bfr[fj][ks] = *(const bf16x8*)&sB[r * 64 + s * 8];
      }
    }
#pragma unroll
    for (int ks = 0; ks < 2; ++ks)
#pragma unroll
      for (int fi = 0; fi < 4; ++fi)
#pragma unroll
        for (int fj = 0; fj < 2; ++fj)
          acc[fi][fj] = __builtin_amdgcn_mfma_f32_16x16x32_bf16(af[fi][ks], bfr[fj][ks], acc[fi][fj], 0, 0, 0);
  }

  // epilogue: activation (block-uniform Z/F) -> bf16 -> sT 64x264 -> dwordx4
  ushort* gout = bnZF ? fout : zout;
  const float* bias = bnZF ? bfb : bz;
  float bv[2];
#pragma unroll
  for (int fj = 0; fj < 2; ++fj)
    bv[fj] = bias[wave * 32 + fj * 16 + lrow];

  __syncthreads();                   // all ds_reads of sA/sB done (sT aliases)
#pragma unroll
  for (int fi = 0; fi < 4; ++fi)
#pragma unroll
    for (int fj = 0; fj < 2; ++fj)
#pragma unroll
      for (int r = 0; r < 4; ++r) {
        float v = acc[fi][fj][r] + bv[fj];
        float o = bnZF ? sigf(v) : (v * sigf(1.702f * v));
        sT[(fi * 16 + quad * 4 + r) * 264 + wave * 32 + fj * 16 + lrow] = f2bf(o);
      }
  __syncthreads();
#pragma unroll
  for (int it = 0; it < 4; ++it) {
    int e = tid + it * 512;           // 2048 segs = 64 rows x 32 segs
    int row = e >> 5, seg = e & 31;
    uint4 v = *(uint4*)&sT[row * 264 + seg * 8];
    *(uint4*)(gout + (size_t)(bm * 64 + row) * 256 + seg * 8) = v;
  }
}

// ---- 3) per-chunk reduction, 2 channels/thread ----
__global__ void scanA_kernel(const ushort* __restrict__ z, const ushort* __restrict__ f,
                             float* __restrict__ Ac, float* __restrict__ Cc) {
  int t = blockIdx.x * blockDim.x + threadIdx.x;   // 0..131071
  int ch2 = t & 1023;
  int j = t >> 10;                                  // 0..127
  const size_t base = (size_t)j * CHUNK * NCH + 2 * ch2;
  const ushort* zp = z + base;
  const ushort* fp = f + base;
  float A0 = 1.0f, C0 = 0.0f, A1 = 1.0f, C1 = 0.0f;
#pragma unroll
  for (int i = 0; i < CHUNK; ++i) {
    ushort2 fv = *(const ushort2*)(fp + (size_t)i * NCH);
    ushort2 zv = *(const ushort2*)(zp + (size_t)i * NCH);
    float f0 = bf2f(fv.x), f1 = bf2f(fv.y);
    float a0 = 1.0f - f0, a1 = 1.0f - f1;
    C0 = fmaf(a0, C0, f0 * bf2f(zv.x)); A0 *= a0;
    C1 = fmaf(a1, C1, f1 * bf2f(zv.y)); A1 *= a1;
  }
  float2 Av = {A0, A1}, Cv = {C0, C1};
  *(float2*)(Ac + (size_t)j * NCH + 2 * ch2) = Av;
  *(float2*)(Cc + (size_t)j * NCH + 2 * ch2) = Cv;
}

// ---- 4) cross-chunk scan: one wave per channel, shfl Hillis-Steele ----
__global__ void scanB_kernel(const float* __restrict__ hidden,
                             const float* __restrict__ Ac, const float* __restrict__ Cc,
                             float* __restrict__ Hs) {
  const int lane = threadIdx.x & 63;
  const int ch = blockIdx.x * 4 + (threadIdx.x >> 6);   // 512 blocks x 4 waves
  const int j0 = 2 * lane, j1 = 2 * lane + 1;
  float a0 = Ac[j0 * NCH + ch], c0 = Cc[j0 * NCH + ch];
  float a1 = Ac[j1 * NCH + ch], c1 = Cc[j1 * NCH + ch];
  float a = a0 * a1;
  float c = fmaf(a1, c0, c1);
#pragma unroll
  for (int d = 1; d < 64; d <<= 1) {
    float pa = __shfl_up(a, d, 64);
    float pc = __shfl_up(c, d, 64);
    if (lane >= d) { c = fmaf(a, pc, c); a *= pa; }
  }
  float xa = __shfl_up(a, 1, 64), xc = __shfl_up(c, 1, 64);
  if (lane == 0) { xa = 1.0f; xc = 0.0f; }
  float h0 = hidden[ch];
  float hs0 = fmaf(xa, h0, xc);
  Hs[j0 * NCH + ch] = hs0;
  Hs[j1 * NCH + ch] = fmaf(a0, hs0, c0);
}

// ---- 5) replay within chunk, 2 channels/thread, fp32 out ----
__global__ void scanC_kernel(const ushort* __restrict__ z, const ushort* __restrict__ f,
                             const float* __restrict__ Hs, float* __restrict__ out) {
  int t = blockIdx.x * blockDim.x + threadIdx.x;   // 0..131071
  int ch2 = t & 1023;
  int j = t >> 10;
  float2 hv = *(const float2*)(Hs + (size_t)j * NCH + 2 * ch2);
  float h0 = hv.x, h1 = hv.y;
  const size_t base = (size_t)j * CHUNK * NCH + 2 * ch2;
  const ushort* zp = z + base;
  const ushort* fp = f + base;
  float* op = out + base;
#pragma unroll
  for (int i = 0; i < CHUNK; ++i) {
    ushort2 fv = *(const ushort2*)(fp + (size_t)i * NCH);
    ushort2 zv = *(const ushort2*)(zp + (size_t)i * NCH);
    float f0 = bf2f(fv.x), f1 = bf2f(fv.y);
    h0 = fmaf(f0, bf2f(zv.x) - h0, h0);
    h1 = fmaf(f1, bf2f(zv.y) - h1, h1);
    float2 o = {h0, h1};
    *(float2*)(op + (size_t)i * NCH) = o;
  }
  if (j == NCHUNK - 1) {
    float2 o = {h0, h1};
    *(float2*)(out + (size_t)SEQn * NCH + 2 * ch2) = o;   // h_last row
  }
}

extern "C" void kernel_launch(void* const* d_in, const int* in_sizes, int n_in,
                              void* d_out, int out_size, void* d_ws, size_t ws_size,
                              hipStream_t stream) {
  const float* X      = (const float*)d_in[0];
  const float* hidden = (const float*)d_in[1];
  const float* Wz     = (const float*)d_in[2];
  const float* bz     = (const float*)d_in[3];
  const float* Wf     = (const float*)d_in[4];
  const float* bfb    = (const float*)d_in[5];
  float* out = (float*)d_out;

  char* ws = (char*)d_ws;
  ushort* zbf = (ushort*)ws;                       // 16,777,216 B
  ushort* fbf = (ushort*)(ws + 16777216);          // 16,777,216 B
  ushort* Xbf = (ushort*)(ws + 33554432);          // 16,781,312 B (dead after gemm)
  ushort* Bm  = (ushort*)(ws + 50335744);          //    524,288 B
  // aliased over Xbf (used only after gemm completes):
  float* Ac = (float*)(ws + 33554432);
  float* Cc = (float*)(ws + 34603008);
  float* Hs = (float*)(ws + 35651584);

  pack_kernel<<<9218, 256, 0, stream>>>(X, Wz, Wf, Xbf, Bm);
  gemm_kernel<<<1024, 512, 0, stream>>>(Xbf, Bm, bz, bfb, zbf, fbf);
  scanA_kernel<<<512, 256, 0, stream>>>(zbf, fbf, Ac, Cc);
  scanB_kernel<<<512, 256, 0, stream>>>(hidden, Ac, Cc, Hs);
  scanC_kernel<<<512, 256, 0, stream>>>(zbf, fbf, Hs, out);
}